// Round 1
// baseline (905.724 us; speedup 1.0000x reference)
//
#include <hip/hip_runtime.h>
#include <stdint.h>

// BiRNN: T=512, B=128, D=H=256, fp32 in/out, bf16 MFMA compute.
// Kernel 1 (xw_gemm): xW = x@W_xh + b per direction, stored as PACKED bf16
//   inside d_out's fp32 slots (fwd: u16 idx [0,256) of each row; bwd: [512,768)).
// Kernel 2 (birnn_rec): per-batch-partitioned recurrence, W_hh frags in VGPRs,
//   h in LDS double buffer, overwrites d_out with fp32 h. Final states appended.

typedef short sh4   __attribute__((ext_vector_type(4)));
typedef short sh8   __attribute__((ext_vector_type(8)));
typedef float f32x4 __attribute__((ext_vector_type(4)));

#define TT 512
#define BB 128
#define HH 256

__device__ __forceinline__ unsigned short f2bf(float x) {
    union { float f; unsigned u; } v; v.f = x;
    unsigned r = v.u + 0x7FFFu + ((v.u >> 16) & 1u);   // RNE
    return (unsigned short)(r >> 16);
}
__device__ __forceinline__ float bf2f(unsigned short b) {
    union { unsigned u; float f; } v; v.u = ((unsigned)b) << 16; return v.f;
}
__device__ __forceinline__ float tanh_fast(float x) {
    float ax = __builtin_fabsf(x);
    float e  = __expf(-2.0f * ax);                      // e^{-2|x|}
    float r  = (1.0f - e) * __builtin_amdgcn_rcpf(1.0f + e);
    return __builtin_copysignf(r, x);
}

// ---------------- Kernel 1: xW GEMM ----------------
// grid (1024, 4), block 256. Tile: M=64 rows (t*B+b), N=128 of 512 combined cols.
// A(bf16) [64][264] LDS, B(bf16, transposed [n][k]) [128][264] LDS.
#define LDK 264   // padded stride in shorts (16B-aligned rows, bank-spread)

__global__ __launch_bounds__(256) void xw_gemm(
    const float* __restrict__ x,     // [65536,256]
    const float* __restrict__ Wf,    // [256,256] row-major [d][h]
    const float* __restrict__ biasf, // [256]
    const float* __restrict__ Wb,
    const float* __restrict__ biasb,
    unsigned short* __restrict__ outp)  // u16 view of d_out
{
    __shared__ __align__(16) short Alds[64 * LDK];
    __shared__ __align__(16) short Blds[128 * LDK];
    const int tid = threadIdx.x;
    const int R0  = blockIdx.x * 64;
    const int C0  = blockIdx.y * 128;       // 0..511 combined
    const int dir = C0 >> 8;                // 0 fwd, 1 bwd
    const int jb  = C0 & 255;
    const float* W    = dir ? Wb    : Wf;
    const float* bias = dir ? biasb : biasf;

    // stage A: 64x256 fp32 -> bf16
#pragma unroll
    for (int i = 0; i < 16; ++i) {
        int idx = tid + i * 256;            // 0..4095
        int r = idx >> 6, c4 = idx & 63;
        float4 v = *(const float4*)(x + (size_t)(R0 + r) * 256 + c4 * 4);
        sh4 s;
        s.x = (short)f2bf(v.x); s.y = (short)f2bf(v.y);
        s.z = (short)f2bf(v.z); s.w = (short)f2bf(v.w);
        *(sh4*)&Alds[r * LDK + c4 * 4] = s;
    }
    // stage B transposed: Blds[n][k]
#pragma unroll
    for (int i = 0; i < 32; ++i) {
        int idx = tid + i * 256;            // 0..8191
        int k = idx >> 5, nq = idx & 31;
        float4 v = *(const float4*)(W + (size_t)k * 256 + jb + nq * 4);
        Blds[(nq * 4 + 0) * LDK + k] = (short)f2bf(v.x);
        Blds[(nq * 4 + 1) * LDK + k] = (short)f2bf(v.y);
        Blds[(nq * 4 + 2) * LDK + k] = (short)f2bf(v.z);
        Blds[(nq * 4 + 3) * LDK + k] = (short)f2bf(v.w);
    }
    __syncthreads();

    const int w  = tid >> 6;     // wave 0..3: n-range [32w, 32w+32)
    const int l  = tid & 63;
    const int li = l & 15, lq = l >> 4;

    f32x4 acc[4][2];
#pragma unroll
    for (int mt = 0; mt < 4; ++mt)
#pragma unroll
        for (int nt = 0; nt < 2; ++nt) acc[mt][nt] = (f32x4){0.f, 0.f, 0.f, 0.f};

#pragma unroll
    for (int kf = 0; kf < 8; ++kf) {
        sh8 a[4], b[2];
#pragma unroll
        for (int mt = 0; mt < 4; ++mt)
            a[mt] = *(const sh8*)&Alds[(mt * 16 + li) * LDK + kf * 32 + lq * 8];
#pragma unroll
        for (int nt = 0; nt < 2; ++nt)
            b[nt] = *(const sh8*)&Blds[(w * 32 + nt * 16 + li) * LDK + kf * 32 + lq * 8];
#pragma unroll
        for (int mt = 0; mt < 4; ++mt)
#pragma unroll
            for (int nt = 0; nt < 2; ++nt)
                acc[mt][nt] = __builtin_amdgcn_mfma_f32_16x16x32_bf16(a[mt], b[nt], acc[mt][nt], 0, 0, 0);
    }

    // epilogue: pack bf16 into u16 slots of d_out
#pragma unroll
    for (int mt = 0; mt < 4; ++mt) {
#pragma unroll
        for (int nt = 0; nt < 2; ++nt) {
            int n = w * 32 + nt * 16 + li;
            int j = jb + n;
            float bv = bias[j];
#pragma unroll
            for (int r = 0; r < 4; ++r) {
                int row = R0 + mt * 16 + lq * 4 + r;   // C/D: row=(lane>>4)*4+reg, col=lane&15
                outp[(size_t)row * 1024 + dir * 512 + j] = f2bf(acc[mt][nt][r] + bv);
            }
        }
    }
}

// ---------------- Kernel 2: recurrence ----------------
// grid 16 blocks x 256 thr. Block bx: dir=bx>>3, batch rows [16*(bx&7), +16).
// Wave w owns output cols [64w, 64w+64): W_hh frags wf[4][8] resident in VGPRs.
// h (bf16) in LDS: layout [kgrp=n>>3][m][n&7], double buffered.
__global__ __launch_bounds__(256, 1) void birnn_rec(
    const float* __restrict__ Whf,
    const float* __restrict__ Whb,
    float* __restrict__ out)
{
    __shared__ __align__(16) unsigned short hbuf[2][4096];  // 2 x 8KB
    const int tid = threadIdx.x;
    const int w  = tid >> 6, l = tid & 63;
    const int li = l & 15, lq = l >> 4;
    const int bx = blockIdx.x;
    const int dir   = bx >> 3;
    const int bbase = (bx & 7) * 16;
    const float* Whh = dir ? Whb : Whf;
    const int N0 = w * 64;

    // Load W_hh fragments (constant over the whole T loop): wf[nt][kf]
    sh8 wf[4][8];
#pragma unroll
    for (int nt = 0; nt < 4; ++nt)
#pragma unroll
        for (int kf = 0; kf < 8; ++kf) {
            sh8 t;
#pragma unroll
            for (int j = 0; j < 8; ++j) {
                int k = kf * 32 + lq * 8 + j;          // B-frag: k=(lane>>4)*8+j
                int n = N0 + nt * 16 + li;             //         n=lane&15
                t[j] = (short)f2bf(Whh[(size_t)k * 256 + n]);
            }
            wf[nt][kf] = t;
        }

    // zero h0
    for (int i = tid; i < 2048; i += 256) ((unsigned*)hbuf[0])[i] = 0u;
    __syncthreads();

    unsigned short* o16 = (unsigned short*)out;
    const size_t FSTATE = (size_t)TT * BB * 512;       // start of f_H

    // preload xw for s=0
    float xw[4][4];
    {
        int t0 = dir ? (TT - 1) : 0;
#pragma unroll
        for (int nt = 0; nt < 4; ++nt)
#pragma unroll
            for (int r = 0; r < 4; ++r) {
                int b = bbase + lq * 4 + r;
                int j = N0 + nt * 16 + li;
                xw[nt][r] = bf2f(o16[((size_t)t0 * BB + b) * 1024 + dir * 512 + j]);
            }
    }

    for (int s = 0; s < TT; ++s) {
        const int t   = dir ? (TT - 1 - s) : s;
        const int cur = s & 1, nxt = cur ^ 1;

        // A-frags for h_s from LDS
        sh8 a[8];
#pragma unroll
        for (int kf = 0; kf < 8; ++kf)
            a[kf] = *(const sh8*)&hbuf[cur][((kf * 4 + lq) * 16 + li) * 8];

        // prefetch next step's xw (row t+-1: untouched during step s; s=511 reads garbage, unused)
        float xwn[4][4];
        {
            int sp = (s < TT - 1) ? (s + 1) : s;
            int tp = dir ? (TT - 1 - sp) : sp;
#pragma unroll
            for (int nt = 0; nt < 4; ++nt)
#pragma unroll
                for (int r = 0; r < 4; ++r) {
                    int b = bbase + lq * 4 + r;
                    int j = N0 + nt * 16 + li;
                    xwn[nt][r] = bf2f(o16[((size_t)tp * BB + b) * 1024 + dir * 512 + j]);
                }
        }

        // h_s @ W_hh
        f32x4 acc[4];
#pragma unroll
        for (int nt = 0; nt < 4; ++nt) acc[nt] = (f32x4){0.f, 0.f, 0.f, 0.f};
#pragma unroll
        for (int kf = 0; kf < 8; ++kf)
#pragma unroll
            for (int nt = 0; nt < 4; ++nt)
                acc[nt] = __builtin_amdgcn_mfma_f32_16x16x32_bf16(a[kf], wf[nt][kf], acc[nt], 0, 0, 0);

        // epilogue: tanh, write fp32 out, write bf16 h into next LDS buffer
#pragma unroll
        for (int nt = 0; nt < 4; ++nt) {
            int n = N0 + nt * 16 + li;
#pragma unroll
            for (int r = 0; r < 4; ++r) {
                int m = lq * 4 + r;
                int b = bbase + m;
                float v = tanh_fast(acc[nt][r] + xw[nt][r]);
                out[((size_t)t * BB + b) * 512 + dir * 256 + n] = v;
                hbuf[nxt][((n >> 3) * 16 + m) * 8 + (n & 7)] = f2bf(v);
                if (s == TT - 1)
                    out[FSTATE + (size_t)dir * (BB * HH) + (size_t)b * HH + n] = v;
            }
        }
#pragma unroll
        for (int nt = 0; nt < 4; ++nt)
#pragma unroll
            for (int r = 0; r < 4; ++r) xw[nt][r] = xwn[nt][r];

        __syncthreads();
    }
}

extern "C" void kernel_launch(void* const* d_in, const int* in_sizes, int n_in,
                              void* d_out, int out_size, void* d_ws, size_t ws_size,
                              hipStream_t stream)
{
    const float* x   = (const float*)d_in[0];
    const float* Wxf = (const float*)d_in[1];
    const float* Whf = (const float*)d_in[2];
    const float* bhf = (const float*)d_in[3];
    const float* Wxb = (const float*)d_in[4];
    const float* Whb = (const float*)d_in[5];
    const float* bhb = (const float*)d_in[6];
    float* out = (float*)d_out;

    hipLaunchKernelGGL(xw_gemm, dim3(1024, 4), dim3(256), 0, stream,
                       x, Wxf, bhf, Wxb, bhb, (unsigned short*)d_out);
    hipLaunchKernelGGL(birnn_rec, dim3(16), dim3(256), 0, stream,
                       Whf, Whb, out);
}

// Round 2
// 775.987 us; speedup vs baseline: 1.1672x; 1.1672x over previous
//
#include <hip/hip_runtime.h>
#include <stdint.h>

// Fully fused BiRNN: T=512, B=128, D=H=256, fp32 in/out, bf16 MFMA compute.
// 16 blocks (8 batch-groups x 2 directions) x 512 threads (8 waves).
// Per block: W_xh and W_hh fragments resident in VGPRs (wave owns 32 output
// cols); per step: stage x-tile (prefetched 2 steps ahead) + h-tile in LDS,
// 32 MFMA/wave (16 for x@Wx, 16 for h@Wh), tanh epilogue, fp32 store.
// Barrier is raw "s_waitcnt lgkmcnt(0); s_barrier" — global traffic is
// race-free (x read-only, h-stores never re-read), so no vmcnt drain needed.

typedef short sh8   __attribute__((ext_vector_type(8)));
typedef float f32x4 __attribute__((ext_vector_type(4)));

#define TT 512
#define BB 128
#define HH 256
#define LDH 264   // u16 stride per m-row: 528 B = 33*16 B (16B-aligned, bank-rotating)

__device__ __forceinline__ unsigned short f2bf(float x) {
    union { float f; unsigned u; } v; v.f = x;
    unsigned r = v.u + 0x7FFFu + ((v.u >> 16) & 1u);   // RNE
    return (unsigned short)(r >> 16);
}
__device__ __forceinline__ float tanh_fast(float x) {
    float e = __expf(-2.0f * __builtin_fabsf(x));
    float r = (1.0f - e) * __builtin_amdgcn_rcpf(1.0f + e);
    return __builtin_copysignf(r, x);
}
// LDS-only barrier: __syncthreads() would drain vmcnt(0) (global store acks)
// every step; our cross-wave communication is exclusively through LDS.
__device__ __forceinline__ void bar_lds() {
    asm volatile("s_waitcnt lgkmcnt(0)\n\ts_barrier" ::: "memory");
}

__global__ __launch_bounds__(512, 2) void birnn_fused(
    const float* __restrict__ x,
    const float* __restrict__ Wxf, const float* __restrict__ Whf,
    const float* __restrict__ bhf,
    const float* __restrict__ Wxb, const float* __restrict__ Whb,
    const float* __restrict__ bhb,
    float* __restrict__ out)
{
    __shared__ __align__(16) unsigned short hb[2][16 * LDH];    // h state, bf16
    __shared__ __align__(16) unsigned short xb[2][16 * LDH];    // x tile, bf16

    const int tid = threadIdx.x;
    const int w  = tid >> 6, l = tid & 63;
    const int li = l & 15, lq = l >> 4;
    const int bx = blockIdx.x;
    const int dir   = bx >> 3;
    const int bbase = (bx & 7) * 16;
    const float* Wx = dir ? Wxb : Wxf;
    const float* Wh = dir ? Whb : Whf;
    const float* bs = dir ? bhb : bhf;
    const int N0 = w * 32;

    // Resident weight fragments (B-operand layout: n=lane&15, k=(lane>>4)*8+j)
    sh8 wfx[2][8], wfh[2][8];
#pragma unroll
    for (int nt = 0; nt < 2; ++nt)
#pragma unroll
        for (int kf = 0; kf < 8; ++kf) {
            sh8 tx, th;
#pragma unroll
            for (int j = 0; j < 8; ++j) {
                int k = kf * 32 + lq * 8 + j;
                int n = N0 + nt * 16 + li;
                tx[j] = (short)f2bf(Wx[(size_t)k * HH + n]);
                th[j] = (short)f2bf(Wh[(size_t)k * HH + n]);
            }
            wfx[nt][kf] = tx; wfh[nt][kf] = th;
        }
    const float bias0 = bs[N0 + li];
    const float bias1 = bs[N0 + 16 + li];

    // h0 = 0
    for (int i = tid; i < 16 * LDH / 2; i += 512) ((unsigned*)hb[0])[i] = 0u;

    // x staging: thread handles row sm, 8 cols at sk
    const int sm = tid >> 5;
    const int sk = (tid & 31) * 8;
    const float* xrow = x + ((size_t)bbase + sm) * HH + sk;   // + t*BB*HH per step

    const int t0 = dir ? TT - 1 : 0;
    const int t1 = dir ? TT - 2 : 1;
    {   // stage x(t0) into xb[0]
        const float* p = xrow + (size_t)t0 * BB * HH;
        float4 v0 = *(const float4*)p;
        float4 v1 = *(const float4*)(p + 4);
        sh8 sv;
        sv[0] = (short)f2bf(v0.x); sv[1] = (short)f2bf(v0.y);
        sv[2] = (short)f2bf(v0.z); sv[3] = (short)f2bf(v0.w);
        sv[4] = (short)f2bf(v1.x); sv[5] = (short)f2bf(v1.y);
        sv[6] = (short)f2bf(v1.z); sv[7] = (short)f2bf(v1.w);
        *(sh8*)&xb[0][sm * LDH + sk] = sv;
    }
    float4 xg0, xg1;   // in-flight x(t1) for staging during step 0
    {
        const float* p = xrow + (size_t)t1 * BB * HH;
        xg0 = *(const float4*)p;
        xg1 = *(const float4*)(p + 4);
    }
    bar_lds();

    float* orow = out + ((size_t)t0 * BB + bbase) * 512 + dir * HH;
    const ptrdiff_t ostep = dir ? -(ptrdiff_t)(BB * 512) : (ptrdiff_t)(BB * 512);
    const size_t FST = (size_t)TT * BB * 512;   // final-state region

    for (int s = 0; s < TT; ++s) {
        const int cur = s & 1, nxt = cur ^ 1;

        // stage x(s+1) into xb[nxt]; kick off load of x(s+2)
        {
            sh8 sv;
            sv[0] = (short)f2bf(xg0.x); sv[1] = (short)f2bf(xg0.y);
            sv[2] = (short)f2bf(xg0.z); sv[3] = (short)f2bf(xg0.w);
            sv[4] = (short)f2bf(xg1.x); sv[5] = (short)f2bf(xg1.y);
            sv[6] = (short)f2bf(xg1.z); sv[7] = (short)f2bf(xg1.w);
            *(sh8*)&xb[nxt][sm * LDH + sk] = sv;
            const int s2 = (s + 2 < TT) ? s + 2 : s;       // clamp; value unused at tail
            const int t2 = dir ? TT - 1 - s2 : s2;
            const float* p = xrow + (size_t)t2 * BB * HH;
            xg0 = *(const float4*)p;
            xg1 = *(const float4*)(p + 4);
        }

        // MFMA: acc = x_t @ Wx + h_s @ Wh  (4 independent 8-deep chains)
        f32x4 acch[2], accx[2];
#pragma unroll
        for (int nt = 0; nt < 2; ++nt) {
            acch[nt] = (f32x4){0.f, 0.f, 0.f, 0.f};
            accx[nt] = (f32x4){0.f, 0.f, 0.f, 0.f};
        }
#pragma unroll
        for (int kf = 0; kf < 8; ++kf) {
            sh8 ah = *(const sh8*)&hb[cur][li * LDH + kf * 32 + lq * 8];
            sh8 ax = *(const sh8*)&xb[cur][li * LDH + kf * 32 + lq * 8];
#pragma unroll
            for (int nt = 0; nt < 2; ++nt) {
                acch[nt] = __builtin_amdgcn_mfma_f32_16x16x32_bf16(ah, wfh[nt][kf], acch[nt], 0, 0, 0);
                accx[nt] = __builtin_amdgcn_mfma_f32_16x16x32_bf16(ax, wfx[nt][kf], accx[nt], 0, 0, 0);
            }
        }

        // epilogue: tanh, fp32 store, bf16 h into next buffer
        float vv[2][4];
#pragma unroll
        for (int nt = 0; nt < 2; ++nt) {
            const int n = N0 + nt * 16 + li;
            const float bv = nt ? bias1 : bias0;
#pragma unroll
            for (int r = 0; r < 4; ++r) {
                const int m = lq * 4 + r;
                float v = tanh_fast(acch[nt][r] + accx[nt][r] + bv);
                vv[nt][r] = v;
                orow[(size_t)m * 512 + n] = v;
                hb[nxt][m * LDH + n] = f2bf(v);
            }
        }
        if (s == TT - 1) {
#pragma unroll
            for (int nt = 0; nt < 2; ++nt) {
                const int n = N0 + nt * 16 + li;
#pragma unroll
                for (int r = 0; r < 4; ++r) {
                    const int m = lq * 4 + r;
                    out[FST + (size_t)dir * (BB * HH) + (size_t)(bbase + m) * HH + n] = vv[nt][r];
                }
            }
        }
        orow += ostep;
        bar_lds();
    }
}

extern "C" void kernel_launch(void* const* d_in, const int* in_sizes, int n_in,
                              void* d_out, int out_size, void* d_ws, size_t ws_size,
                              hipStream_t stream)
{
    const float* x   = (const float*)d_in[0];
    const float* Wxf = (const float*)d_in[1];
    const float* Whf = (const float*)d_in[2];
    const float* bhf = (const float*)d_in[3];
    const float* Wxb = (const float*)d_in[4];
    const float* Whb = (const float*)d_in[5];
    const float* bhb = (const float*)d_in[6];

    hipLaunchKernelGGL(birnn_fused, dim3(16), dim3(512), 0, stream,
                       x, Wxf, Whf, bhf, Wxb, Whb, bhb, (float*)d_out);
}